// Round 8
// baseline (183.514 us; speedup 1.0000x reference)
//
#include <hip/hip_runtime.h>
#include <hip/hip_bf16.h>
#include <math.h>

// Problem constants: B=16, C=OUP=64, H=W=128, HW=16384, M=10
#define NB   16
#define NC   64
#define NH   128
#define NW   128
#define NHW  16384
#define NM   10
#define SA   52      // padded LDS row stride for dwfinal (52 mod 8 = 4)

// ---------------------------------------------------------------------------
// K0: g[b,c] = mean over HW of x[b,c,:,:]   (f64 accumulation, float4 loads)
// ---------------------------------------------------------------------------
__global__ __launch_bounds__(256) void k_gmean(const float* __restrict__ x,
                                               double* __restrict__ g) {
    int bc = blockIdx.x;                     // 0..1023
    const float* xp = x + (size_t)bc * NHW;
    double s = 0.0;
    for (int i = threadIdx.x; i < NHW / 4; i += 256) {
        float4 v = ((const float4*)xp)[i];
        s += (double)v.x + (double)v.y + (double)v.z + (double)v.w;
    }
    for (int off = 32; off; off >>= 1) s += __shfl_down(s, off);
    __shared__ double red[4];
    int wid = threadIdx.x >> 6, lane = threadIdx.x & 63;
    if (lane == 0) red[wid] = s;
    __syncthreads();
    if (threadIdx.x == 0)
        g[bc] = (red[0] + red[1] + red[2] + red[3]) * (1.0 / (double)NHW);
}

// ---------------------------------------------------------------------------
// K0b: gn[b] = max(sqrt(sum_c g^2), 1e-8), exact sequential f64 order.
// ---------------------------------------------------------------------------
__global__ __launch_bounds__(64) void k_misc(const double* __restrict__ g,
                                             double* __restrict__ gn) {
    if (threadIdx.x == 0) {
        int b = blockIdx.x;
        const double* gb = g + b * NC;
        double gsq = 0.0;
        for (int c = 0; c < NC; ++c) gsq += gb[c] * gb[c];
        gn[b] = fmax(sqrt(gsq), 1e-8);
    }
}

// ---------------------------------------------------------------------------
// K1: x_c = 1x1 conv + cosine-sim S. Split-K: Xs[32][256] (32KB) + Wt (16KB)
// = 48KB -> 3 blocks/CU = 12 waves/CU. Thread: 8px x 8o. c order 0..63
// ascending across the two halves -> bit-identical S and xc.
// ---------------------------------------------------------------------------
__global__ __launch_bounds__(256) void k_conv1_S(
        const float* __restrict__ x, const float* __restrict__ W,
        const double* __restrict__ g, const double* __restrict__ gn,
        float* __restrict__ xc, double* __restrict__ S) {
    __shared__ __align__(16) float Xs[32 * 256];   // 32 KB
    __shared__ __align__(16) float WtL[64 * 64];   // 16 KB, WtL[c*64+o]=W[o][c]
    int bid = blockIdx.x;
    int b = bid >> 6, k0 = (bid & 63) * 256;
    int tid = threadIdx.x;
    const float* xb = x + (size_t)b * NC * NHW + k0;

    for (int e = tid; e < 4096; e += 256) {
        int c = e >> 6, o = e & 63;
        WtL[e] = W[o * 64 + c];
    }

    int pg = tid & 31, og = tid >> 5;
    int px0 = pg * 8, o0 = og * 8;
    float acc[8][8];
#pragma unroll
    for (int i = 0; i < 8; ++i)
#pragma unroll
        for (int j = 0; j < 8; ++j) acc[i][j] = 0.f;
    double num = 0.0, sq = 0.0;
    const double* gb = g + b * NC;

#pragma unroll
    for (int h = 0; h < 2; ++h) {
        if (h) __syncthreads();              // prior compute done with Xs
        for (int e = tid; e < 2048; e += 256) {
            int cl = e >> 6, p4 = (e & 63) << 2;
            *(float4*)&Xs[cl * 256 + p4] =
                *(const float4*)&xb[(size_t)(32*h + cl) * NHW + p4];
        }
        __syncthreads();

        // S partials: px = tid, c ascending (32h+cl)
#pragma unroll 8
        for (int cl = 0; cl < 32; ++cl) {
            double v = (double)Xs[cl * 256 + tid];
            num += gb[32*h + cl] * v;
            sq  += v * v;
        }
        // GEMM partials
#pragma unroll 4
        for (int cl = 0; cl < 32; ++cl) {
            int cg = 32*h + cl;
            float4 xa  = *(float4*)&Xs[cl * 256 + px0];
            float4 xb2 = *(float4*)&Xs[cl * 256 + px0 + 4];
            float4 wa  = *(float4*)&WtL[cg * 64 + o0];
            float4 wb2 = *(float4*)&WtL[cg * 64 + o0 + 4];
            float xr[8] = {xa.x, xa.y, xa.z, xa.w, xb2.x, xb2.y, xb2.z, xb2.w};
            float wr[8] = {wa.x, wa.y, wa.z, wa.w, wb2.x, wb2.y, wb2.z, wb2.w};
#pragma unroll
            for (int i = 0; i < 8; ++i)
#pragma unroll
                for (int j = 0; j < 8; ++j)
                    acc[i][j] = fmaf(wr[i], xr[j], acc[i][j]);
        }
    }

    double xn = fmax(sqrt(sq), 1e-8);
    S[(size_t)b * NHW + k0 + tid] = num / (gn[b] * xn);

    float* xcb = xc + (size_t)b * NC * NHW + k0;
#pragma unroll
    for (int i = 0; i < 8; ++i) {
        float4 s0, s1;
        s0.x = acc[i][0]; s0.y = acc[i][1]; s0.z = acc[i][2]; s0.w = acc[i][3];
        s1.x = acc[i][4]; s1.y = acc[i][5]; s1.z = acc[i][6]; s1.w = acc[i][7];
        *(float4*)&xcb[(size_t)(o0 + i) * NHW + px0] = s0;
        *(float4*)&xcb[(size_t)(o0 + i) * NHW + px0 + 4] = s1;
    }
}

// ---------------------------------------------------------------------------
// K2a: per-quarter min/max partials (4 blocks per batch)
// ---------------------------------------------------------------------------
__global__ __launch_bounds__(256) void k_minmax(const double* __restrict__ S,
                                                double* __restrict__ pmn,
                                                double* __restrict__ pmx) {
    int blk = blockIdx.x, b = blk >> 2, part = blk & 3;
    const double* Sb = S + (size_t)b * NHW + part * 4096;
    int tid = threadIdx.x;
    double mn = 1e300, mx = -1e300;
    for (int i = tid; i < 4096; i += 256) {
        double v = Sb[i];
        mn = fmin(mn, v); mx = fmax(mx, v);
    }
    for (int off = 32; off; off >>= 1) {
        mn = fmin(mn, __shfl_down(mn, off));
        mx = fmax(mx, __shfl_down(mx, off));
    }
    __shared__ double rmn[4], rmx[4];
    int wid = tid >> 6, lane = tid & 63;
    if (lane == 0) { rmn[wid] = mn; rmx[wid] = mx; }
    __syncthreads();
    if (tid == 0) {
        pmn[blk] = fmin(fmin(rmn[0], rmn[1]), fmin(rmn[2], rmn[3]));
        pmx[blk] = fmax(fmax(rmx[0], rmx[1]), fmax(rmx[2], rmx[3]));
    }
}

// ---------------------------------------------------------------------------
// K2b: per-quarter histogram partials (levels recomputed exactly per block)
// ---------------------------------------------------------------------------
__global__ __launch_bounds__(256) void k_hist(const double* __restrict__ S,
                                              const double* __restrict__ pmn,
                                              const double* __restrict__ pmx,
                                              double* __restrict__ pbins) {
    int blk = blockIdx.x, b = blk >> 2, part = blk & 3;
    double a = fmin(fmin(pmn[4*b], pmn[4*b+1]), fmin(pmn[4*b+2], pmn[4*b+3]));
    double z = fmax(fmax(pmx[4*b], pmx[4*b+1]), fmax(pmx[4*b+2], pmx[4*b+3]));
    double lv[NM];
#pragma unroll
    for (int m = 0; m < NM; ++m) lv[m] = a + (z - a) * ((double)m / 9.0);

    const double* Sb = S + (size_t)b * NHW + part * 4096;
    int tid = threadIdx.x;
    double bins[NM];
#pragma unroll
    for (int m = 0; m < NM; ++m) bins[m] = 0.0;
    for (int i = tid; i < 4096; i += 256) {
        double v = Sb[i];
#pragma unroll
        for (int m = 0; m < NM; ++m) {
            double d = fabs(lv[m] - v);
            if (d < 0.05) bins[m] += 1.0 - d;
        }
    }
#pragma unroll
    for (int m = 0; m < NM; ++m)
        for (int off = 32; off; off >>= 1) bins[m] += __shfl_down(bins[m], off);
    __shared__ double wb[4][NM];
    int wid = tid >> 6, lane = tid & 63;
    if (lane == 0) {
#pragma unroll
        for (int m = 0; m < NM; ++m) wb[wid][m] = bins[m];
    }
    __syncthreads();
    if (tid == 0) {
#pragma unroll
        for (int m = 0; m < NM; ++m)
            pbins[blk * NM + m] = wb[0][m] + wb[1][m] + wb[2][m] + wb[3][m];
    }
}

// ---------------------------------------------------------------------------
// K3: per-batch tail: combine partials -> ratio/levels -> Cf -> P -> softmax
//     -> Lp.  One block per batch (all scans already done).
// ---------------------------------------------------------------------------
__global__ __launch_bounds__(256) void k_chain(
        const double* __restrict__ pmn, const double* __restrict__ pmx,
        const double* __restrict__ pbins,
        const float* __restrict__ fc1w, const float* __restrict__ fc1b,
        const float* __restrict__ ph1w, const float* __restrict__ ph1b,
        const float* __restrict__ ph2w, const float* __restrict__ ph2b,
        const float* __restrict__ ph3w, const float* __restrict__ ph3b,
        double* __restrict__ levelsOut, float* __restrict__ LpOut) {
    int b = blockIdx.x, tid = threadIdx.x;
    __shared__ double levS[NM];
    __shared__ float ratio[NM];
    if (tid == 0) {
        double a = fmin(fmin(pmn[4*b], pmn[4*b+1]), fmin(pmn[4*b+2], pmn[4*b+3]));
        double z = fmax(fmax(pmx[4*b], pmx[4*b+1]), fmax(pmx[4*b+2], pmx[4*b+3]));
        for (int m = 0; m < NM; ++m) levS[m] = a + (z - a) * ((double)m / 9.0);
        double den = 0.0;
        for (int m = 0; m < NM; ++m) {
            double cs = ((pbins[(4*b)*NM+m] + pbins[(4*b+1)*NM+m])
                        + pbins[(4*b+2)*NM+m]) + pbins[(4*b+3)*NM+m];
            den += cs;
            ratio[m] = (float)(cs / den);
        }
    }
    __syncthreads();

    __shared__ float CfL[640];
    for (int idx = tid; idx < 640; idx += 256) {
        int rm = idx >> 6, o = idx & 63;
        CfL[idx] = ratio[rm] * fc1w[o*2+0] + (float)levS[rm] * fc1w[o*2+1] + fc1b[o];
    }
    __syncthreads();

    __shared__ float P1[640], P2[640], P3[640];
    for (int idx = tid; idx < 640; idx += 256) {
        int o = idx / 10, m = idx - o * 10;
        float a1 = ph1b[o], a2 = ph2b[o], a3 = ph3b[o];
        for (int c2 = 0; c2 < NC; ++c2) {
            float cq = CfL[c2*10 + m];
            a1 = fmaf(ph1w[o*NC + c2], cq, a1);
            a2 = fmaf(ph2w[o*NC + c2], cq, a2);
            a3 = fmaf(ph3w[o*NC + c2], cq, a3);
        }
        P1[idx] = a1; P2[idx] = a2; P3[idx] = a3;
    }
    __syncthreads();

    __shared__ float XL[100];
    if (tid < 100) {
        int m = tid / 10, n = tid - (tid/10)*10;
        float acc = 0.f;
        for (int c2 = 0; c2 < NC; ++c2)
            acc = fmaf(P1[c2*10 + m], P2[c2*10 + n], acc);
        XL[tid] = acc;
    }
    __syncthreads();
    if (tid < NM) {
        float mxr = XL[tid*10];
        for (int n = 1; n < NM; ++n) mxr = fmaxf(mxr, XL[tid*10 + n]);
        float e[NM], sum = 0.f;
        for (int n = 0; n < NM; ++n) { e[n] = expf(XL[tid*10+n] - mxr); sum += e[n]; }
        for (int n = 0; n < NM; ++n) XL[tid*10+n] = e[n] / sum;
    }
    __syncthreads();

    for (int idx = tid; idx < 640; idx += 256) {
        int c2 = idx / 10, n = idx - (idx/10)*10;
        float acc = 0.f;
#pragma unroll
        for (int m = 0; m < NM; ++m) acc = fmaf(P3[c2*10 + m], XL[m*10 + n], acc);
        LpOut[b*640 + idx] = acc;
    }
    if (tid < NM) levelsOut[b*NM + tid] = levS[tid];
}

// ---------------------------------------------------------------------------
// K3b: per-pixel gather precompute (ONCE per pixel).
// ---------------------------------------------------------------------------
__global__ __launch_bounds__(256) void k_vgath(
        const double* __restrict__ S, const double* __restrict__ levels,
        float* __restrict__ vg, float* __restrict__ Sf) {
    int P = blockIdx.x * 256 + threadIdx.x;
    int b = P >> 14, k = P & (NHW - 1);
    __shared__ double levL[NM];
    if (threadIdx.x < NM) levL[threadIdx.x] = levels[b*NM + threadIdx.x];
    __syncthreads();
    const double* Sb = S + (size_t)b * NHW;
    float* vgb = vg + (size_t)b * NM * NHW;
#pragma unroll
    for (int i = 0; i < NM; ++i) {
        int j = i * NHW + k;
        int p = j / 10;
        int m = j - p * 10;
        double d = fabs(levL[m] - Sb[p]);
        vgb[i * NHW + k] = (d < 0.05) ? (float)(1.0 - d) : 0.f;
    }
    Sf[P] = (float)Sb[k];
}

// ---------------------------------------------------------------------------
// K4: fused depthwise chain + final fusion, 32x32 tiles, TWO CHANNELS/block.
// Masks/index/vg loads computed once per task; fma doubled in-stream.
//   A  (s0): 44x44 region, stride SA=52
//   Bf (s1): 44x40, stride SA
//   A  (s2): 40x40, stride SA
//   Bf (s3): 40x32, stride SA
//   s4+fusion: 32x32
// ---------------------------------------------------------------------------
__global__ __launch_bounds__(256) void k_dwfinal(
        const float* __restrict__ xc, const float* __restrict__ x,
        const float* __restrict__ vg, const float* __restrict__ Sf,
        const float* __restrict__ Lp,
        const float* __restrict__ pw1, const float* __restrict__ pw2,
        const float* __restrict__ pw3, const float* __restrict__ pw4,
        const float* __restrict__ gamma, const float* __restrict__ beta,
        const float* __restrict__ bn1g, const float* __restrict__ bn1b,
        const float* __restrict__ bn2g, const float* __restrict__ bn2b,
        const float* __restrict__ wconv2, float* __restrict__ out) {
    int tile = blockIdx.x, cp = blockIdx.y, b = blockIdx.z;
    int R0 = (tile >> 2) * 32, C0 = (tile & 3) * 32;
    const float inv = 0.9999950000374997f;   // 1/sqrt(1+1e-5)
    float s0[2], v0[2], s1[2], v1[2], s2[2], v2[2], s3[2], v3[2], s4[2], v4[2];
    float w1[2][5], w2[2][5], w3[2][5], w4[2][5];
    float Acc[2], Bcc[2], S1c[2];
#pragma unroll
    for (int ch = 0; ch < 2; ++ch) {
        int c = cp*2 + ch;
        s0[ch] = gamma[0*NC+c]*inv; v0[ch] = beta[0*NC+c];
        s1[ch] = gamma[1*NC+c]*inv; v1[ch] = beta[1*NC+c];
        s2[ch] = gamma[2*NC+c]*inv; v2[ch] = beta[2*NC+c];
        s3[ch] = gamma[3*NC+c]*inv; v3[ch] = beta[3*NC+c];
        s4[ch] = gamma[4*NC+c]*inv; v4[ch] = beta[4*NC+c];
#pragma unroll
        for (int q = 0; q < 5; ++q) {
            w1[ch][q] = pw1[c*5+q]; w2[ch][q] = pw2[c*5+q];
            w3[ch][q] = pw3[c*5+q]; w4[ch][q] = pw4[c*5+q];
        }
        Acc[ch] = wconv2[c] * (bn2g[c] * inv);
        Bcc[ch] = bn2b[c] + bn1b[c];
        S1c[ch] = bn1g[c] * inv;
    }

    __shared__ __align__(16) float A[2*44*SA];   // 18304 B
    __shared__ __align__(16) float Bfs[2*44*SA]; // 18304 B
    __shared__ float LpL[2][NM];
    int tid = threadIdx.x;
    if (tid < 2*NM) LpL[tid/NM][tid%NM] = Lp[b*640 + (cp*2 + tid/NM)*10 + tid%NM];
    const float* src0 = xc + (size_t)(b*NC + cp*2) * NHW;
    const float* src1 = src0 + NHW;

    // stage0: load + bn0 -> A[ch][44][44], zeros outside (44x11 = 484 tasks)
    for (int t = tid; t < 484; t += 256) {
        int r = t / 11, g4 = t - r*11;
        int gy = R0 - 6 + r, gx0 = C0 - 6 + 4*g4;
        bool rowOK = (unsigned)gy < NH;
        bool full4 = (unsigned)gx0 <= (unsigned)(NW-4);
        bool m0 = (unsigned)(gx0+0) < NW, m1 = (unsigned)(gx0+1) < NW;
        bool m2 = (unsigned)(gx0+2) < NW, m3 = (unsigned)(gx0+3) < NW;
        const float* srcs[2] = {src0, src1};
#pragma unroll
        for (int ch = 0; ch < 2; ++ch) {
            float4 v = make_float4(0.f, 0.f, 0.f, 0.f);
            if (rowOK) {
                const float* rowp = srcs[ch] + gy*NW;
                if (full4) v = *(const float4*)(rowp + gx0);
                else {
                    float* pv = (float*)&v;
#pragma unroll
                    for (int u = 0; u < 4; ++u) {
                        int gx = gx0 + u;
                        if ((unsigned)gx < NW) pv[u] = rowp[gx];
                    }
                }
            }
            float4 w;
            w.x = (rowOK && m0) ? fmaf(v.x, s0[ch], v0[ch]) : 0.f;
            w.y = (rowOK && m1) ? fmaf(v.y, s0[ch], v0[ch]) : 0.f;
            w.z = (rowOK && m2) ? fmaf(v.z, s0[ch], v0[ch]) : 0.f;
            w.w = (rowOK && m3) ? fmaf(v.w, s0[ch], v0[ch]) : 0.f;
            *(float4*)&A[ch*44*SA + r*SA + 4*g4] = w;
        }
    }
    __syncthreads();

    // stage1: h +-2 + bn1 -> Bf[ch][44][40]; task = 8 cols (44x5 = 220 tasks)
    for (int t = tid; t < 220; t += 256) {
        int r = t / 5, gp = t - r*5;
        int gy = R0 - 6 + r;
        bool rowOK = (unsigned)gy < NH;
        bool cm[8];
#pragma unroll
        for (int u = 0; u < 8; ++u)
            cm[u] = rowOK && ((unsigned)(C0 - 4 + 8*gp + u) < NW);
#pragma unroll
        for (int ch = 0; ch < 2; ++ch) {
            float xw[12];
            *(float4*)&xw[0] = *(float4*)&A[ch*44*SA + r*SA + 8*gp];
            *(float4*)&xw[4] = *(float4*)&A[ch*44*SA + r*SA + 8*gp + 4];
            *(float4*)&xw[8] = *(float4*)&A[ch*44*SA + r*SA + 8*gp + 8];
            float o[8];
#pragma unroll
            for (int u = 0; u < 8; ++u) {
                float acc = 0.f;
#pragma unroll
                for (int q = 0; q < 5; ++q) acc = fmaf(w1[ch][q], xw[u+q], acc);
                o[u] = cm[u] ? fmaf(acc, s1[ch], v1[ch]) : 0.f;
            }
            *(float4*)&Bfs[ch*44*SA + r*SA + 8*gp]     = *(float4*)&o[0];
            *(float4*)&Bfs[ch*44*SA + r*SA + 8*gp + 4] = *(float4*)&o[4];
        }
    }
    __syncthreads();

    // stage2: v +-2 + bn2 -> A[ch][40][40]; task = 4r x 4c (10x10 = 100)
    if (tid < 100) {
        int rg = tid / 10, g2 = tid - rg*10;
        bool colOK[4];
#pragma unroll
        for (int u = 0; u < 4; ++u)
            colOK[u] = (unsigned)(C0 - 4 + 4*g2 + u) < NW;
#pragma unroll
        for (int ch = 0; ch < 2; ++ch) {
            float ys[8][4];
#pragma unroll
            for (int m = 0; m < 8; ++m)
                *(float4*)&ys[m][0] = *(float4*)&Bfs[ch*44*SA + (4*rg + m)*SA + 4*g2];
#pragma unroll
            for (int rr = 0; rr < 4; ++rr) {
                int gy = R0 - 4 + 4*rg + rr;
                bool rowOK = (unsigned)gy < NH;
                float o[4];
#pragma unroll
                for (int u = 0; u < 4; ++u) {
                    float acc = 0.f;
#pragma unroll
                    for (int p = 0; p < 5; ++p) acc = fmaf(w2[ch][p], ys[rr+p][u], acc);
                    o[u] = (rowOK && colOK[u]) ? fmaf(acc, s2[ch], v2[ch]) : 0.f;
                }
                *(float4*)&A[ch*44*SA + (4*rg + rr)*SA + 4*g2] = *(float4*)o;
            }
        }
    }
    __syncthreads();

    // stage3: h dil2 +-4 + bn3 -> Bf[ch][40][32]; task = 8 cols (40x4 = 160)
    if (tid < 160) {
        int r = tid >> 2, gp = tid & 3;
        int gy = R0 - 4 + r;
        bool rowOK = (unsigned)gy < NH;
#pragma unroll
        for (int ch = 0; ch < 2; ++ch) {
            float xw[16];
            *(float4*)&xw[0]  = *(float4*)&A[ch*44*SA + r*SA + 8*gp];
            *(float4*)&xw[4]  = *(float4*)&A[ch*44*SA + r*SA + 8*gp + 4];
            *(float4*)&xw[8]  = *(float4*)&A[ch*44*SA + r*SA + 8*gp + 8];
            *(float4*)&xw[12] = *(float4*)&A[ch*44*SA + r*SA + 8*gp + 12];
            float o[8];
#pragma unroll
            for (int u = 0; u < 8; ++u) {
                float acc = 0.f;
#pragma unroll
                for (int q = 0; q < 5; ++q) acc = fmaf(w3[ch][q], xw[u+2*q], acc);
                o[u] = rowOK ? fmaf(acc, s3[ch], v3[ch]) : 0.f;
            }
            *(float4*)&Bfs[ch*44*SA + r*SA + 8*gp]     = *(float4*)&o[0];
            *(float4*)&Bfs[ch*44*SA + r*SA + 8*gp + 4] = *(float4*)&o[4];
        }
    }
    __syncthreads();

    // stage4: v dil2 +-4 + bn4 + fusion; task = 2 same-parity rows x 4 cols
    // (16 gr x 8 g2 = 128 tasks); vg/Sf loads shared across both channels.
    if (tid < 128) {
        int gr = tid >> 3, g2 = tid & 7;
        int base = (gr & 1) + 4*(gr >> 1);
        float ys[2][6][4];
#pragma unroll
        for (int ch = 0; ch < 2; ++ch)
#pragma unroll
            for (int m = 0; m < 6; ++m)
                *(float4*)&ys[ch][m][0] =
                    *(float4*)&Bfs[ch*44*SA + (base + 2*m)*SA + 4*g2];
        const float* vgb = vg + (size_t)b * NM * NHW;
        const float* Sfb = Sf + (size_t)b * NHW;
#pragma unroll
        for (int j = 0; j < 2; ++j) {
            int ro = base + 2*j;
            int kbase = (R0 + ro) * NW + C0 + 4*g2;
            float vr[NM][4];
#pragma unroll
            for (int i = 0; i < NM; ++i)
                *(float4*)&vr[i][0] = *(const float4*)&vgb[i * NHW + kbase];
            float4 skv = *(const float4*)&Sfb[kbase];
            const float* skp = (const float*)&skv;
#pragma unroll
            for (int ch = 0; ch < 2; ++ch) {
                size_t xbase = (size_t)(b*NC + cp*2 + ch) * NHW + kbase;
                float4 xv = *(const float4*)&x[xbase];
                const float* xvp = (const float*)&xv;
                float res[4];
#pragma unroll
                for (int u = 0; u < 4; ++u) {
                    float acc = 0.f;
#pragma unroll
                    for (int p = 0; p < 5; ++p)
                        acc = fmaf(w4[ch][p], ys[ch][j+p][u], acc);
                    float xcen = fmaf(acc, s4[ch], v4[ch]);
                    float R = 0.f;
#pragma unroll
                    for (int i = 0; i < NM; ++i) R = fmaf(LpL[ch][i], vr[i][u], R);
                    float pre = fmaf(Acc[ch], skp[u], Bcc[ch]) + S1c[ch] * R + xcen;
                    float att = 1.0f / (1.0f + expf(-pre));
                    res[u] = xvp[u] * att;
                }
                *(float4*)&out[xbase] = *(float4*)res;
            }
        }
    }
}

// ---------------------------------------------------------------------------
extern "C" void kernel_launch(void* const* d_in, const int* in_sizes, int n_in,
                              void* d_out, int out_size, void* d_ws, size_t ws_size,
                              hipStream_t stream) {
    (void)in_sizes; (void)n_in; (void)out_size; (void)ws_size;
    const float* x      = (const float*)d_in[0];
    const float* wconv1 = (const float*)d_in[1];
    const float* pw1    = (const float*)d_in[2];
    const float* pw2    = (const float*)d_in[3];
    const float* pw3    = (const float*)d_in[4];
    const float* pw4    = (const float*)d_in[5];
    const float* pgam   = (const float*)d_in[6];
    const float* pbet   = (const float*)d_in[7];
    const float* bn1g   = (const float*)d_in[8];
    const float* bn1b   = (const float*)d_in[9];
    const float* bn2g   = (const float*)d_in[10];
    const float* bn2b   = (const float*)d_in[11];
    const float* fc1w   = (const float*)d_in[12];
    const float* fc1b   = (const float*)d_in[13];
    const float* ph1w   = (const float*)d_in[14];
    const float* ph1b   = (const float*)d_in[15];
    const float* ph2w   = (const float*)d_in[16];
    const float* ph2b   = (const float*)d_in[17];
    const float* ph3w   = (const float*)d_in[18];
    const float* ph3b   = (const float*)d_in[19];
    const float* wconv2 = (const float*)d_in[20];
    float* out = (float*)d_out;

    // workspace layout (~78 MB), doubles first for 8B alignment
    float*  ws    = (float*)d_ws;
    float*  xc    = ws;                                 // 16777216 f32 (64MB)
    double* Sd    = (double*)(ws + 16777216);           // 262144 f64 (2MB)
    double* g     = Sd + NB * NHW;                      // 1024 f64
    double* lev   = g + NB * NC;                        // 160 f64
    double* gn    = lev + NB * NM;                      // 16 f64
    double* pmn   = gn + NB;                            // 64 f64
    double* pmx   = pmn + 64;                           // 64 f64
    double* pbins = pmx + 64;                           // 640 f64
    float*  Lp    = (float*)(pbins + 640);              // 10240 f32
    float*  vg    = Lp + NB * 640;                      // 2621440 f32 (10.5MB)
    float*  Sf    = vg + NB * NM * NHW;                 // 262144 f32 (1MB)

    k_gmean<<<NB * NC, 256, 0, stream>>>(x, g);
    k_misc<<<NB, 64, 0, stream>>>(g, gn);
    k_conv1_S<<<NB * NHW / 256, 256, 0, stream>>>(x, wconv1, g, gn, xc, Sd);
    k_minmax<<<NB * 4, 256, 0, stream>>>(Sd, pmn, pmx);
    k_hist<<<NB * 4, 256, 0, stream>>>(Sd, pmn, pmx, pbins);
    k_chain<<<NB, 256, 0, stream>>>(pmn, pmx, pbins, fc1w, fc1b,
                                    ph1w, ph1b, ph2w, ph2b, ph3w, ph3b,
                                    lev, Lp);
    k_vgath<<<NB * NHW / 256, 256, 0, stream>>>(Sd, lev, vg, Sf);
    k_dwfinal<<<dim3(16, 32, NB), 256, 0, stream>>>(
        xc, x, vg, Sf, Lp, pw1, pw2, pw3, pw4, pgam, pbet,
        bn1g, bn1b, bn2g, bn2b, wconv2, out);
}

// Round 9
// 159.398 us; speedup vs baseline: 1.1513x; 1.1513x over previous
//
#include <hip/hip_runtime.h>
#include <hip/hip_bf16.h>
#include <math.h>

// Problem constants: B=16, C=OUP=64, H=W=128, HW=16384, M=10
#define NB   16
#define NC   64
#define NH   128
#define NW   128
#define NHW  16384
#define NM   10

// ---------------------------------------------------------------------------
// K0: g[b,c] = mean over HW of x[b,c,:,:]   (f64 accumulation, float4 loads)
// ---------------------------------------------------------------------------
__global__ __launch_bounds__(256) void k_gmean(const float* __restrict__ x,
                                               double* __restrict__ g) {
    int bc = blockIdx.x;                     // 0..1023
    const float* xp = x + (size_t)bc * NHW;
    double s = 0.0;
    for (int i = threadIdx.x; i < NHW / 4; i += 256) {
        float4 v = ((const float4*)xp)[i];
        s += (double)v.x + (double)v.y + (double)v.z + (double)v.w;
    }
    for (int off = 32; off; off >>= 1) s += __shfl_down(s, off);
    __shared__ double red[4];
    int wid = threadIdx.x >> 6, lane = threadIdx.x & 63;
    if (lane == 0) red[wid] = s;
    __syncthreads();
    if (threadIdx.x == 0)
        g[bc] = (red[0] + red[1] + red[2] + red[3]) * (1.0 / (double)NHW);
}

// ---------------------------------------------------------------------------
// K0b: block 0 transposes W -> Wt[c][o]; blocks 1..16 compute gn[b] (exact
// sequential f64 order -> bit-identical S).
// ---------------------------------------------------------------------------
__global__ __launch_bounds__(256) void k_misc(const float* __restrict__ W,
                                              const double* __restrict__ g,
                                              float* __restrict__ Wt,
                                              double* __restrict__ gn) {
    if (blockIdx.x == 0) {
        for (int e = threadIdx.x; e < 64 * 64; e += 256) {
            int c = e >> 6, o = e & 63;
            Wt[c * 64 + o] = W[o * 64 + c];
        }
    } else if (threadIdx.x == 0) {
        int b = blockIdx.x - 1;
        const double* gb = g + b * NC;
        double gsq = 0.0;
        for (int c = 0; c < NC; ++c) gsq += gb[c] * gb[c];
        gn[b] = fmax(sqrt(gsq), 1e-8);
    }
}

// ---------------------------------------------------------------------------
// K1: x_c = 1x1 conv + cosine-sim S.  NO LDS, NO BARRIERS.
// Thread = 1 pixel: xv[64] in VGPRs (64 coalesced dword loads), S from regs
// (sequential c order -> bit-identical), then 8 passes x 8 outputs with W
// via wave-uniform s_load (Wt rows, dwordx8 broadcast).
// ---------------------------------------------------------------------------
__global__ __launch_bounds__(256, 4) void k_conv1_S(
        const float* __restrict__ x, const float* __restrict__ Wt,
        const double* __restrict__ g, const double* __restrict__ gn,
        float* __restrict__ xc, double* __restrict__ S) {
    int P = blockIdx.x * 256 + threadIdx.x;
    int b = P >> 14, k = P & (NHW - 1);
    const float* xb = x + (size_t)b * NC * NHW + k;

    // load all 64 channel values (each load coalesced across the wave)
    float xv[NC];
#pragma unroll
    for (int c = 0; c < NC; ++c) xv[c] = xb[(size_t)c * NHW];

    // S phase: same sequential f64 order as all passing rounds
    {
        const double* gb = g + b * NC;
        double num = 0.0, sq = 0.0;
#pragma unroll
        for (int c = 0; c < NC; ++c) {
            double v = (double)xv[c];
            num += gb[c] * v;
            sq  += v * v;
        }
        double xn = fmax(sqrt(sq), 1e-8);
        S[P] = num / (gn[b] * xn);
    }

    // GEMM: 8 passes of 8 outputs; W wave-uniform -> s_load broadcast
    float* xcb = xc + (size_t)b * NC * NHW + k;
    for (int p = 0; p < 8; ++p) {
        int o0 = p * 8;
        float acc[8];
#pragma unroll
        for (int j = 0; j < 8; ++j) acc[j] = 0.f;
#pragma unroll
        for (int c = 0; c < NC; ++c) {
            const float* wr = Wt + c * 64 + o0;   // SGPR base + const -> s_load
#pragma unroll
            for (int j = 0; j < 8; ++j)
                acc[j] = fmaf(wr[j], xv[c], acc[j]);
        }
#pragma unroll
        for (int j = 0; j < 8; ++j)
            xcb[(size_t)(o0 + j) * NHW] = acc[j];
    }
}

// ---------------------------------------------------------------------------
// K2a: per-quarter min/max partials (4 blocks per batch)
// ---------------------------------------------------------------------------
__global__ __launch_bounds__(256) void k_minmax(const double* __restrict__ S,
                                                double* __restrict__ pmn,
                                                double* __restrict__ pmx) {
    int blk = blockIdx.x, b = blk >> 2, part = blk & 3;
    const double* Sb = S + (size_t)b * NHW + part * 4096;
    int tid = threadIdx.x;
    double mn = 1e300, mx = -1e300;
    for (int i = tid; i < 4096; i += 256) {
        double v = Sb[i];
        mn = fmin(mn, v); mx = fmax(mx, v);
    }
    for (int off = 32; off; off >>= 1) {
        mn = fmin(mn, __shfl_down(mn, off));
        mx = fmax(mx, __shfl_down(mx, off));
    }
    __shared__ double rmn[4], rmx[4];
    int wid = tid >> 6, lane = tid & 63;
    if (lane == 0) { rmn[wid] = mn; rmx[wid] = mx; }
    __syncthreads();
    if (tid == 0) {
        pmn[blk] = fmin(fmin(rmn[0], rmn[1]), fmin(rmn[2], rmn[3]));
        pmx[blk] = fmax(fmax(rmx[0], rmx[1]), fmax(rmx[2], rmx[3]));
    }
}

// ---------------------------------------------------------------------------
// K2b: per-quarter histogram partials (levels recomputed exactly per block)
// ---------------------------------------------------------------------------
__global__ __launch_bounds__(256) void k_hist(const double* __restrict__ S,
                                              const double* __restrict__ pmn,
                                              const double* __restrict__ pmx,
                                              double* __restrict__ pbins) {
    int blk = blockIdx.x, b = blk >> 2, part = blk & 3;
    double a = fmin(fmin(pmn[4*b], pmn[4*b+1]), fmin(pmn[4*b+2], pmn[4*b+3]));
    double z = fmax(fmax(pmx[4*b], pmx[4*b+1]), fmax(pmx[4*b+2], pmx[4*b+3]));
    double lv[NM];
#pragma unroll
    for (int m = 0; m < NM; ++m) lv[m] = a + (z - a) * ((double)m / 9.0);

    const double* Sb = S + (size_t)b * NHW + part * 4096;
    int tid = threadIdx.x;
    double bins[NM];
#pragma unroll
    for (int m = 0; m < NM; ++m) bins[m] = 0.0;
    for (int i = tid; i < 4096; i += 256) {
        double v = Sb[i];
#pragma unroll
        for (int m = 0; m < NM; ++m) {
            double d = fabs(lv[m] - v);
            if (d < 0.05) bins[m] += 1.0 - d;
        }
    }
#pragma unroll
    for (int m = 0; m < NM; ++m)
        for (int off = 32; off; off >>= 1) bins[m] += __shfl_down(bins[m], off);
    __shared__ double wb[4][NM];
    int wid = tid >> 6, lane = tid & 63;
    if (lane == 0) {
#pragma unroll
        for (int m = 0; m < NM; ++m) wb[wid][m] = bins[m];
    }
    __syncthreads();
    if (tid == 0) {
#pragma unroll
        for (int m = 0; m < NM; ++m)
            pbins[blk * NM + m] = wb[0][m] + wb[1][m] + wb[2][m] + wb[3][m];
    }
}

// ---------------------------------------------------------------------------
// K3: per-batch tail: combine partials -> ratio/levels -> Cf -> P -> softmax
//     -> Lp.  One block per batch.
// ---------------------------------------------------------------------------
__global__ __launch_bounds__(256) void k_chain(
        const double* __restrict__ pmn, const double* __restrict__ pmx,
        const double* __restrict__ pbins,
        const float* __restrict__ fc1w, const float* __restrict__ fc1b,
        const float* __restrict__ ph1w, const float* __restrict__ ph1b,
        const float* __restrict__ ph2w, const float* __restrict__ ph2b,
        const float* __restrict__ ph3w, const float* __restrict__ ph3b,
        double* __restrict__ levelsOut, float* __restrict__ LpOut) {
    int b = blockIdx.x, tid = threadIdx.x;
    __shared__ double levS[NM];
    __shared__ float ratio[NM];
    if (tid == 0) {
        double a = fmin(fmin(pmn[4*b], pmn[4*b+1]), fmin(pmn[4*b+2], pmn[4*b+3]));
        double z = fmax(fmax(pmx[4*b], pmx[4*b+1]), fmax(pmx[4*b+2], pmx[4*b+3]));
        for (int m = 0; m < NM; ++m) levS[m] = a + (z - a) * ((double)m / 9.0);
        double den = 0.0;
        for (int m = 0; m < NM; ++m) {
            double cs = ((pbins[(4*b)*NM+m] + pbins[(4*b+1)*NM+m])
                        + pbins[(4*b+2)*NM+m]) + pbins[(4*b+3)*NM+m];
            den += cs;
            ratio[m] = (float)(cs / den);
        }
    }
    __syncthreads();

    __shared__ float CfL[640];
    for (int idx = tid; idx < 640; idx += 256) {
        int rm = idx >> 6, o = idx & 63;
        CfL[idx] = ratio[rm] * fc1w[o*2+0] + (float)levS[rm] * fc1w[o*2+1] + fc1b[o];
    }
    __syncthreads();

    __shared__ float P1[640], P2[640], P3[640];
    for (int idx = tid; idx < 640; idx += 256) {
        int o = idx / 10, m = idx - o * 10;
        float a1 = ph1b[o], a2 = ph2b[o], a3 = ph3b[o];
        for (int c2 = 0; c2 < NC; ++c2) {
            float cq = CfL[c2*10 + m];
            a1 = fmaf(ph1w[o*NC + c2], cq, a1);
            a2 = fmaf(ph2w[o*NC + c2], cq, a2);
            a3 = fmaf(ph3w[o*NC + c2], cq, a3);
        }
        P1[idx] = a1; P2[idx] = a2; P3[idx] = a3;
    }
    __syncthreads();

    __shared__ float XL[100];
    if (tid < 100) {
        int m = tid / 10, n = tid - (tid/10)*10;
        float acc = 0.f;
        for (int c2 = 0; c2 < NC; ++c2)
            acc = fmaf(P1[c2*10 + m], P2[c2*10 + n], acc);
        XL[tid] = acc;
    }
    __syncthreads();
    if (tid < NM) {
        float mxr = XL[tid*10];
        for (int n = 1; n < NM; ++n) mxr = fmaxf(mxr, XL[tid*10 + n]);
        float e[NM], sum = 0.f;
        for (int n = 0; n < NM; ++n) { e[n] = expf(XL[tid*10+n] - mxr); sum += e[n]; }
        for (int n = 0; n < NM; ++n) XL[tid*10+n] = e[n] / sum;
    }
    __syncthreads();

    for (int idx = tid; idx < 640; idx += 256) {
        int c2 = idx / 10, n = idx - (idx/10)*10;
        float acc = 0.f;
#pragma unroll
        for (int m = 0; m < NM; ++m) acc = fmaf(P3[c2*10 + m], XL[m*10 + n], acc);
        LpOut[b*640 + idx] = acc;
    }
    if (tid < NM) levelsOut[b*NM + tid] = levS[tid];
}

// ---------------------------------------------------------------------------
// K3b: per-pixel gather precompute (ONCE per pixel).
// ---------------------------------------------------------------------------
__global__ __launch_bounds__(256) void k_vgath(
        const double* __restrict__ S, const double* __restrict__ levels,
        float* __restrict__ vg, float* __restrict__ Sf) {
    int P = blockIdx.x * 256 + threadIdx.x;
    int b = P >> 14, k = P & (NHW - 1);
    __shared__ double levL[NM];
    if (threadIdx.x < NM) levL[threadIdx.x] = levels[b*NM + threadIdx.x];
    __syncthreads();
    const double* Sb = S + (size_t)b * NHW;
    float* vgb = vg + (size_t)b * NM * NHW;
#pragma unroll
    for (int i = 0; i < NM; ++i) {
        int j = i * NHW + k;
        int p = j / 10;
        int m = j - p * 10;
        double d = fabs(levL[m] - Sb[p]);
        vgb[i * NHW + k] = (d < 0.05) ? (float)(1.0 - d) : 0.f;
    }
    Sf[P] = (float)Sb[k];
}

// ---------------------------------------------------------------------------
// K4: fused depthwise chain + final fusion, 32x64 output tiles (26 KB LDS).
// EXACT round-6 version (measured 71 us) — do not restructure.
// ---------------------------------------------------------------------------
__global__ __launch_bounds__(256) void k_dwfinal(
        const float* __restrict__ xc, const float* __restrict__ x,
        const float* __restrict__ vg, const float* __restrict__ Sf,
        const float* __restrict__ Lp,
        const float* __restrict__ pw1, const float* __restrict__ pw2,
        const float* __restrict__ pw3, const float* __restrict__ pw4,
        const float* __restrict__ gamma, const float* __restrict__ beta,
        const float* __restrict__ bn1g, const float* __restrict__ bn1b,
        const float* __restrict__ bn2g, const float* __restrict__ bn2b,
        const float* __restrict__ wconv2, float* __restrict__ out) {
    int tile = blockIdx.x, c = blockIdx.y, b = blockIdx.z;
    int R0 = (tile >> 1) * 32, C0 = (tile & 1) * 64;
    const float inv = 0.9999950000374997f;   // 1/sqrt(1+1e-5)
    float s0 = gamma[0*NC+c]*inv, b0 = beta[0*NC+c];
    float s1 = gamma[1*NC+c]*inv, b1 = beta[1*NC+c];
    float s2 = gamma[2*NC+c]*inv, b2 = beta[2*NC+c];
    float s3 = gamma[3*NC+c]*inv, b3 = beta[3*NC+c];
    float s4 = gamma[4*NC+c]*inv, b4 = beta[4*NC+c];
    float w1[5], w2[5], w3[5], w4[5];
#pragma unroll
    for (int q = 0; q < 5; ++q) {
        w1[q] = pw1[c*5+q]; w2[q] = pw2[c*5+q];
        w3[q] = pw3[c*5+q]; w4[q] = pw4[c*5+q];
    }
    float Ac = wconv2[c] * (bn2g[c] * inv);
    float Bc = bn2b[c] + bn1b[c];
    float S1 = bn1g[c] * inv;

    __shared__ __align__(16) float A[44*76];   // 13.4 KB
    __shared__ __align__(16) float Bf[44*72];  // 12.7 KB
    __shared__ float LpL[NM];
    const float* src = xc + ((size_t)(b*NC + c)) * NHW;
    int tid = threadIdx.x;

    if (tid < NM) LpL[tid] = Lp[b*640 + c*10 + tid];

    // stage0: load + bn0 -> A[44][76], zeros outside image
    for (int t = tid; t < 44*19; t += 256) {
        int r = t / 19, g2 = t - r*19;
        int gy = R0 - 6 + r, gx0 = C0 - 6 + 4*g2;
        float4 v = make_float4(0.f, 0.f, 0.f, 0.f);
        bool rowOK = (unsigned)gy < NH;
        if (rowOK) {
            const float* rowp = src + gy*NW;
            if ((unsigned)gx0 <= (unsigned)(NW-4)) {
                v = *(const float4*)(rowp + gx0);
            } else {
                float* pv = (float*)&v;
#pragma unroll
                for (int u = 0; u < 4; ++u) {
                    int gx = gx0 + u;
                    if ((unsigned)gx < NW) pv[u] = rowp[gx];
                }
            }
        }
        float4 w;
        w.x = (rowOK && (unsigned)(gx0+0) < NW) ? fmaf(v.x, s0, b0) : 0.f;
        w.y = (rowOK && (unsigned)(gx0+1) < NW) ? fmaf(v.y, s0, b0) : 0.f;
        w.z = (rowOK && (unsigned)(gx0+2) < NW) ? fmaf(v.z, s0, b0) : 0.f;
        w.w = (rowOK && (unsigned)(gx0+3) < NW) ? fmaf(v.w, s0, b0) : 0.f;
        *(float4*)&A[r*76 + 4*g2] = w;
    }
    __syncthreads();

    // stage1: horizontal 1x5 (+-2) + bn1 -> Bf[44][72]
    for (int t = tid; t < 44*18; t += 256) {
        int r = t / 18, g2 = t - r*18;
        float xw[8];
        *(float4*)&xw[0] = *(float4*)&A[r*76 + 4*g2];
        *(float4*)&xw[4] = *(float4*)&A[r*76 + 4*g2 + 4];
        int gy = R0 - 6 + r;
        bool rowOK = (unsigned)gy < NH;
        float o[4];
#pragma unroll
        for (int u = 0; u < 4; ++u) {
            float acc = 0.f;
#pragma unroll
            for (int q = 0; q < 5; ++q) acc = fmaf(w1[q], xw[u+q], acc);
            int gx = C0 - 4 + 4*g2 + u;
            o[u] = (rowOK && (unsigned)gx < NW) ? fmaf(acc, s1, b1) : 0.f;
        }
        *(float4*)&Bf[r*72 + 4*g2] = *(float4*)o;
    }
    __syncthreads();

    // stage2: vertical 5x1 (+-2) + bn2 -> A[40][72]
    for (int t = tid; t < 40*18; t += 256) {
        int r = t / 18, g2 = t - r*18;
        float ys[5][4];
#pragma unroll
        for (int p = 0; p < 5; ++p)
            *(float4*)&ys[p][0] = *(float4*)&Bf[(r+p)*72 + 4*g2];
        int gy = R0 - 4 + r;
        bool rowOK = (unsigned)gy < NH;
        float o[4];
#pragma unroll
        for (int u = 0; u < 4; ++u) {
            float acc = 0.f;
#pragma unroll
            for (int p = 0; p < 5; ++p) acc = fmaf(w2[p], ys[p][u], acc);
            int gx = C0 - 4 + 4*g2 + u;
            o[u] = (rowOK && (unsigned)gx < NW) ? fmaf(acc, s2, b2) : 0.f;
        }
        *(float4*)&A[r*72 + 4*g2] = *(float4*)o;
    }
    __syncthreads();

    // stage3: horizontal 1x5 dil2 (+-4) + bn3 -> Bf[40][64]
    for (int t = tid; t < 40*16; t += 256) {
        int r = t >> 4, g2 = t & 15;
        float xw[12];
        *(float4*)&xw[0] = *(float4*)&A[r*72 + 4*g2];
        *(float4*)&xw[4] = *(float4*)&A[r*72 + 4*g2 + 4];
        *(float4*)&xw[8] = *(float4*)&A[r*72 + 4*g2 + 8];
        int gy = R0 - 4 + r;
        bool rowOK = (unsigned)gy < NH;
        float o[4];
#pragma unroll
        for (int u = 0; u < 4; ++u) {
            float acc = 0.f;
#pragma unroll
            for (int q = 0; q < 5; ++q) acc = fmaf(w3[q], xw[u+2*q], acc);
            o[u] = rowOK ? fmaf(acc, s3, b3) : 0.f;
        }
        *(float4*)&Bf[r*64 + 4*g2] = *(float4*)o;
    }
    __syncthreads();

    // stage4: vertical 5x1 dil2 (+-4) + bn4 -> x_center (regs), then fusion
    const float* vgb = vg + (size_t)b * NM * NHW;
    const float* Sfb = Sf + (size_t)b * NHW;
    for (int t = tid; t < 32*16; t += 256) {
        int r = t >> 4, g2 = t & 15;
        float ys[5][4];
#pragma unroll
        for (int p = 0; p < 5; ++p)
            *(float4*)&ys[p][0] = *(float4*)&Bf[(r+2*p)*64 + 4*g2];
        int kbase = (R0 + r) * NW + C0 + 4*g2;
        size_t xbase = (size_t)(b*NC + c) * NHW + kbase;
        float4 xv = *(const float4*)&x[xbase];
        float4 skv = *(const float4*)&Sfb[kbase];
        const float* xvp = (const float*)&xv;
        const float* skp = (const float*)&skv;
        float vr[NM][4];
#pragma unroll
        for (int i = 0; i < NM; ++i)
            *(float4*)&vr[i][0] = *(const float4*)&vgb[i * NHW + kbase];
        float res[4];
#pragma unroll
        for (int u = 0; u < 4; ++u) {
            float acc = 0.f;
#pragma unroll
            for (int p = 0; p < 5; ++p) acc = fmaf(w4[p], ys[p][u], acc);
            float xcen = fmaf(acc, s4, b4);
            float R = 0.f;
#pragma unroll
            for (int i = 0; i < NM; ++i) R = fmaf(LpL[i], vr[i][u], R);
            float pre = fmaf(Ac, skp[u], Bc) + S1 * R + xcen;
            float att = 1.0f / (1.0f + expf(-pre));
            res[u] = xvp[u] * att;
        }
        *(float4*)&out[xbase] = *(float4*)res;
    }
}

// ---------------------------------------------------------------------------
extern "C" void kernel_launch(void* const* d_in, const int* in_sizes, int n_in,
                              void* d_out, int out_size, void* d_ws, size_t ws_size,
                              hipStream_t stream) {
    (void)in_sizes; (void)n_in; (void)out_size; (void)ws_size;
    const float* x      = (const float*)d_in[0];
    const float* wconv1 = (const float*)d_in[1];
    const float* pw1    = (const float*)d_in[2];
    const float* pw2    = (const float*)d_in[3];
    const float* pw3    = (const float*)d_in[4];
    const float* pw4    = (const float*)d_in[5];
    const float* pgam   = (const float*)d_in[6];
    const float* pbet   = (const float*)d_in[7];
    const float* bn1g   = (const float*)d_in[8];
    const float* bn1b   = (const float*)d_in[9];
    const float* bn2g   = (const float*)d_in[10];
    const float* bn2b   = (const float*)d_in[11];
    const float* fc1w   = (const float*)d_in[12];
    const float* fc1b   = (const float*)d_in[13];
    const float* ph1w   = (const float*)d_in[14];
    const float* ph1b   = (const float*)d_in[15];
    const float* ph2w   = (const float*)d_in[16];
    const float* ph2b   = (const float*)d_in[17];
    const float* ph3w   = (const float*)d_in[18];
    const float* ph3b   = (const float*)d_in[19];
    const float* wconv2 = (const float*)d_in[20];
    float* out = (float*)d_out;

    // workspace layout (~78 MB), doubles first for 8B alignment
    float*  ws    = (float*)d_ws;
    float*  xc    = ws;                                 // 16777216 f32 (64MB)
    double* Sd    = (double*)(ws + 16777216);           // 262144 f64 (2MB)
    double* g     = Sd + NB * NHW;                      // 1024 f64
    double* lev   = g + NB * NC;                        // 160 f64
    double* gn    = lev + NB * NM;                      // 16 f64
    double* pmn   = gn + NB;                            // 64 f64
    double* pmx   = pmn + 64;                           // 64 f64
    double* pbins = pmx + 64;                           // 640 f64
    float*  Lp    = (float*)(pbins + 640);              // 10240 f32
    float*  vg    = Lp + NB * 640;                      // 2621440 f32 (10.5MB)
    float*  Sf    = vg + NB * NM * NHW;                 // 262144 f32 (1MB)
    float*  Wt    = Sf + NB * NHW;                      // 4096 f32

    k_gmean<<<NB * NC, 256, 0, stream>>>(x, g);
    k_misc<<<17, 256, 0, stream>>>(wconv1, g, Wt, gn);
    k_conv1_S<<<NB * NHW / 256, 256, 0, stream>>>(x, Wt, g, gn, xc, Sd);
    k_minmax<<<NB * 4, 256, 0, stream>>>(Sd, pmn, pmx);
    k_hist<<<NB * 4, 256, 0, stream>>>(Sd, pmn, pmx, pbins);
    k_chain<<<NB, 256, 0, stream>>>(pmn, pmx, pbins, fc1w, fc1b,
                                    ph1w, ph1b, ph2w, ph2b, ph3w, ph3b,
                                    lev, Lp);
    k_vgath<<<NB * NHW / 256, 256, 0, stream>>>(Sd, lev, vg, Sf);
    k_dwfinal<<<dim3(8, NC, NB), 256, 0, stream>>>(
        xc, x, vg, Sf, Lp, pw1, pw2, pw3, pw4, pgam, pbet,
        bn1g, bn1b, bn2g, bn2b, wconv2, out);
}

// Round 10
// 158.010 us; speedup vs baseline: 1.1614x; 1.0088x over previous
//
#include <hip/hip_runtime.h>
#include <hip/hip_bf16.h>
#include <math.h>

// Problem constants: B=16, C=OUP=64, H=W=128, HW=16384, M=10
#define NB   16
#define NC   64
#define NH   128
#define NW   128
#define NHW  16384
#define NM   10
#define XCS  16416   // padded xc plane stride (64KB + 128B) -> breaks L2 set aliasing

// ---------------------------------------------------------------------------
// K0: g[b,c] = mean over HW of x[b,c,:,:]   (f64 accumulation, float4 loads)
// ---------------------------------------------------------------------------
__global__ __launch_bounds__(256) void k_gmean(const float* __restrict__ x,
                                               double* __restrict__ g) {
    int bc = blockIdx.x;                     // 0..1023
    const float* xp = x + (size_t)bc * NHW;
    double s = 0.0;
    for (int i = threadIdx.x; i < NHW / 4; i += 256) {
        float4 v = ((const float4*)xp)[i];
        s += (double)v.x + (double)v.y + (double)v.z + (double)v.w;
    }
    for (int off = 32; off; off >>= 1) s += __shfl_down(s, off);
    __shared__ double red[4];
    int wid = threadIdx.x >> 6, lane = threadIdx.x & 63;
    if (lane == 0) red[wid] = s;
    __syncthreads();
    if (threadIdx.x == 0)
        g[bc] = (red[0] + red[1] + red[2] + red[3]) * (1.0 / (double)NHW);
}

// ---------------------------------------------------------------------------
// K0b: block 0 transposes W -> Wt[c][o]; blocks 1..16 compute gn[b] (exact
// sequential f64 order -> bit-identical S).
// ---------------------------------------------------------------------------
__global__ __launch_bounds__(256) void k_misc(const float* __restrict__ W,
                                              const double* __restrict__ g,
                                              float* __restrict__ Wt,
                                              double* __restrict__ gn) {
    if (blockIdx.x == 0) {
        for (int e = threadIdx.x; e < 64 * 64; e += 256) {
            int c = e >> 6, o = e & 63;
            Wt[c * 64 + o] = W[o * 64 + c];
        }
    } else if (threadIdx.x == 0) {
        int b = blockIdx.x - 1;
        const double* gb = g + b * NC;
        double gsq = 0.0;
        for (int c = 0; c < NC; ++c) gsq += gb[c] * gb[c];
        gn[b] = fmax(sqrt(gsq), 1e-8);
    }
}

// ---------------------------------------------------------------------------
// K1: x_c = 1x1 conv + cosine-sim S.  NO LDS, NO BARRIERS.
// Loads issued in bit-reversed plane order (compile-time permutation) to
// spread concurrent L2 requests across set bits; stores to PADDED xc planes.
// S arithmetic order unchanged (ascending c over xv[]) -> bit-identical.
// ---------------------------------------------------------------------------
__global__ __launch_bounds__(256, 4) void k_conv1_S(
        const float* __restrict__ x, const float* __restrict__ Wt,
        const double* __restrict__ g, const double* __restrict__ gn,
        float* __restrict__ xc, double* __restrict__ S) {
    int P = blockIdx.x * 256 + threadIdx.x;
    int b = P >> 14, k = P & (NHW - 1);
    const float* xb = x + (size_t)b * NC * NHW + k;

    // load all 64 channel values; issue order bit-reversed (c is a
    // compile-time constant per unrolled iteration -> xv stays in VGPRs)
    float xv[NC];
#pragma unroll
    for (int cc = 0; cc < NC; ++cc) {
        int c = ((cc & 1) << 5) | ((cc & 2) << 3) | ((cc & 4) << 1)
              | ((cc & 8) >> 1) | ((cc & 16) >> 3) | ((cc & 32) >> 5);
        xv[c] = xb[(size_t)c * NHW];
    }

    // S phase: same sequential f64 order as all passing rounds
    {
        const double* gb = g + b * NC;
        double num = 0.0, sq = 0.0;
#pragma unroll
        for (int c = 0; c < NC; ++c) {
            double v = (double)xv[c];
            num += gb[c] * v;
            sq  += v * v;
        }
        double xn = fmax(sqrt(sq), 1e-8);
        S[P] = num / (gn[b] * xn);
    }

    // GEMM: 8 passes of 8 outputs; W wave-uniform -> s_load broadcast.
    // Pass order bit-reversed to spread the strided store streams.
    float* xcb = xc + (size_t)b * NC * XCS + k;
#pragma unroll
    for (int pp = 0; pp < 8; ++pp) {
        int p = ((pp & 1) << 2) | (pp & 2) | ((pp & 4) >> 2);
        int o0 = p * 8;
        float acc[8];
#pragma unroll
        for (int j = 0; j < 8; ++j) acc[j] = 0.f;
#pragma unroll
        for (int c = 0; c < NC; ++c) {
            const float* wr = Wt + c * 64 + o0;   // SGPR base + const -> s_load
#pragma unroll
            for (int j = 0; j < 8; ++j)
                acc[j] = fmaf(wr[j], xv[c], acc[j]);
        }
#pragma unroll
        for (int j = 0; j < 8; ++j)
            xcb[(size_t)(o0 + j) * XCS] = acc[j];
    }
}

// ---------------------------------------------------------------------------
// K2a: per-quarter min/max partials (4 blocks per batch)
// ---------------------------------------------------------------------------
__global__ __launch_bounds__(256) void k_minmax(const double* __restrict__ S,
                                                double* __restrict__ pmn,
                                                double* __restrict__ pmx) {
    int blk = blockIdx.x, b = blk >> 2, part = blk & 3;
    const double* Sb = S + (size_t)b * NHW + part * 4096;
    int tid = threadIdx.x;
    double mn = 1e300, mx = -1e300;
    for (int i = tid; i < 4096; i += 256) {
        double v = Sb[i];
        mn = fmin(mn, v); mx = fmax(mx, v);
    }
    for (int off = 32; off; off >>= 1) {
        mn = fmin(mn, __shfl_down(mn, off));
        mx = fmax(mx, __shfl_down(mx, off));
    }
    __shared__ double rmn[4], rmx[4];
    int wid = tid >> 6, lane = tid & 63;
    if (lane == 0) { rmn[wid] = mn; rmx[wid] = mx; }
    __syncthreads();
    if (tid == 0) {
        pmn[blk] = fmin(fmin(rmn[0], rmn[1]), fmin(rmn[2], rmn[3]));
        pmx[blk] = fmax(fmax(rmx[0], rmx[1]), fmax(rmx[2], rmx[3]));
    }
}

// ---------------------------------------------------------------------------
// K2b: per-quarter histogram partials (levels recomputed exactly per block)
// ---------------------------------------------------------------------------
__global__ __launch_bounds__(256) void k_hist(const double* __restrict__ S,
                                              const double* __restrict__ pmn,
                                              const double* __restrict__ pmx,
                                              double* __restrict__ pbins) {
    int blk = blockIdx.x, b = blk >> 2, part = blk & 3;
    double a = fmin(fmin(pmn[4*b], pmn[4*b+1]), fmin(pmn[4*b+2], pmn[4*b+3]));
    double z = fmax(fmax(pmx[4*b], pmx[4*b+1]), fmax(pmx[4*b+2], pmx[4*b+3]));
    double lv[NM];
#pragma unroll
    for (int m = 0; m < NM; ++m) lv[m] = a + (z - a) * ((double)m / 9.0);

    const double* Sb = S + (size_t)b * NHW + part * 4096;
    int tid = threadIdx.x;
    double bins[NM];
#pragma unroll
    for (int m = 0; m < NM; ++m) bins[m] = 0.0;
    for (int i = tid; i < 4096; i += 256) {
        double v = Sb[i];
#pragma unroll
        for (int m = 0; m < NM; ++m) {
            double d = fabs(lv[m] - v);
            if (d < 0.05) bins[m] += 1.0 - d;
        }
    }
#pragma unroll
    for (int m = 0; m < NM; ++m)
        for (int off = 32; off; off >>= 1) bins[m] += __shfl_down(bins[m], off);
    __shared__ double wb[4][NM];
    int wid = tid >> 6, lane = tid & 63;
    if (lane == 0) {
#pragma unroll
        for (int m = 0; m < NM; ++m) wb[wid][m] = bins[m];
    }
    __syncthreads();
    if (tid == 0) {
#pragma unroll
        for (int m = 0; m < NM; ++m)
            pbins[blk * NM + m] = wb[0][m] + wb[1][m] + wb[2][m] + wb[3][m];
    }
}

// ---------------------------------------------------------------------------
// K3: per-batch tail: combine partials -> ratio/levels -> Cf -> P -> softmax
//     -> Lp.  One block per batch.
// ---------------------------------------------------------------------------
__global__ __launch_bounds__(256) void k_chain(
        const double* __restrict__ pmn, const double* __restrict__ pmx,
        const double* __restrict__ pbins,
        const float* __restrict__ fc1w, const float* __restrict__ fc1b,
        const float* __restrict__ ph1w, const float* __restrict__ ph1b,
        const float* __restrict__ ph2w, const float* __restrict__ ph2b,
        const float* __restrict__ ph3w, const float* __restrict__ ph3b,
        double* __restrict__ levelsOut, float* __restrict__ LpOut) {
    int b = blockIdx.x, tid = threadIdx.x;
    __shared__ double levS[NM];
    __shared__ float ratio[NM];
    if (tid == 0) {
        double a = fmin(fmin(pmn[4*b], pmn[4*b+1]), fmin(pmn[4*b+2], pmn[4*b+3]));
        double z = fmax(fmax(pmx[4*b], pmx[4*b+1]), fmax(pmx[4*b+2], pmx[4*b+3]));
        for (int m = 0; m < NM; ++m) levS[m] = a + (z - a) * ((double)m / 9.0);
        double den = 0.0;
        for (int m = 0; m < NM; ++m) {
            double cs = ((pbins[(4*b)*NM+m] + pbins[(4*b+1)*NM+m])
                        + pbins[(4*b+2)*NM+m]) + pbins[(4*b+3)*NM+m];
            den += cs;
            ratio[m] = (float)(cs / den);
        }
    }
    __syncthreads();

    __shared__ float CfL[640];
    for (int idx = tid; idx < 640; idx += 256) {
        int rm = idx >> 6, o = idx & 63;
        CfL[idx] = ratio[rm] * fc1w[o*2+0] + (float)levS[rm] * fc1w[o*2+1] + fc1b[o];
    }
    __syncthreads();

    __shared__ float P1[640], P2[640], P3[640];
    for (int idx = tid; idx < 640; idx += 256) {
        int o = idx / 10, m = idx - o * 10;
        float a1 = ph1b[o], a2 = ph2b[o], a3 = ph3b[o];
        for (int c2 = 0; c2 < NC; ++c2) {
            float cq = CfL[c2*10 + m];
            a1 = fmaf(ph1w[o*NC + c2], cq, a1);
            a2 = fmaf(ph2w[o*NC + c2], cq, a2);
            a3 = fmaf(ph3w[o*NC + c2], cq, a3);
        }
        P1[idx] = a1; P2[idx] = a2; P3[idx] = a3;
    }
    __syncthreads();

    __shared__ float XL[100];
    if (tid < 100) {
        int m = tid / 10, n = tid - (tid/10)*10;
        float acc = 0.f;
        for (int c2 = 0; c2 < NC; ++c2)
            acc = fmaf(P1[c2*10 + m], P2[c2*10 + n], acc);
        XL[tid] = acc;
    }
    __syncthreads();
    if (tid < NM) {
        float mxr = XL[tid*10];
        for (int n = 1; n < NM; ++n) mxr = fmaxf(mxr, XL[tid*10 + n]);
        float e[NM], sum = 0.f;
        for (int n = 0; n < NM; ++n) { e[n] = expf(XL[tid*10+n] - mxr); sum += e[n]; }
        for (int n = 0; n < NM; ++n) XL[tid*10+n] = e[n] / sum;
    }
    __syncthreads();

    for (int idx = tid; idx < 640; idx += 256) {
        int c2 = idx / 10, n = idx - (idx/10)*10;
        float acc = 0.f;
#pragma unroll
        for (int m = 0; m < NM; ++m) acc = fmaf(P3[c2*10 + m], XL[m*10 + n], acc);
        LpOut[b*640 + idx] = acc;
    }
    if (tid < NM) levelsOut[b*NM + tid] = levS[tid];
}

// ---------------------------------------------------------------------------
// K3b: per-pixel gather precompute (ONCE per pixel).
// ---------------------------------------------------------------------------
__global__ __launch_bounds__(256) void k_vgath(
        const double* __restrict__ S, const double* __restrict__ levels,
        float* __restrict__ vg, float* __restrict__ Sf) {
    int P = blockIdx.x * 256 + threadIdx.x;
    int b = P >> 14, k = P & (NHW - 1);
    __shared__ double levL[NM];
    if (threadIdx.x < NM) levL[threadIdx.x] = levels[b*NM + threadIdx.x];
    __syncthreads();
    const double* Sb = S + (size_t)b * NHW;
    float* vgb = vg + (size_t)b * NM * NHW;
#pragma unroll
    for (int i = 0; i < NM; ++i) {
        int j = i * NHW + k;
        int p = j / 10;
        int m = j - p * 10;
        double d = fabs(levL[m] - Sb[p]);
        vgb[i * NHW + k] = (d < 0.05) ? (float)(1.0 - d) : 0.f;
    }
    Sf[P] = (float)Sb[k];
}

// ---------------------------------------------------------------------------
// K4: fused depthwise chain + final fusion, 32x64 output tiles (26 KB LDS).
// EXACT round-6 structure (measured 71 us); only xc plane stride -> XCS.
// ---------------------------------------------------------------------------
__global__ __launch_bounds__(256) void k_dwfinal(
        const float* __restrict__ xc, const float* __restrict__ x,
        const float* __restrict__ vg, const float* __restrict__ Sf,
        const float* __restrict__ Lp,
        const float* __restrict__ pw1, const float* __restrict__ pw2,
        const float* __restrict__ pw3, const float* __restrict__ pw4,
        const float* __restrict__ gamma, const float* __restrict__ beta,
        const float* __restrict__ bn1g, const float* __restrict__ bn1b,
        const float* __restrict__ bn2g, const float* __restrict__ bn2b,
        const float* __restrict__ wconv2, float* __restrict__ out) {
    int tile = blockIdx.x, c = blockIdx.y, b = blockIdx.z;
    int R0 = (tile >> 1) * 32, C0 = (tile & 1) * 64;
    const float inv = 0.9999950000374997f;   // 1/sqrt(1+1e-5)
    float s0 = gamma[0*NC+c]*inv, b0 = beta[0*NC+c];
    float s1 = gamma[1*NC+c]*inv, b1 = beta[1*NC+c];
    float s2 = gamma[2*NC+c]*inv, b2 = beta[2*NC+c];
    float s3 = gamma[3*NC+c]*inv, b3 = beta[3*NC+c];
    float s4 = gamma[4*NC+c]*inv, b4 = beta[4*NC+c];
    float w1[5], w2[5], w3[5], w4[5];
#pragma unroll
    for (int q = 0; q < 5; ++q) {
        w1[q] = pw1[c*5+q]; w2[q] = pw2[c*5+q];
        w3[q] = pw3[c*5+q]; w4[q] = pw4[c*5+q];
    }
    float Ac = wconv2[c] * (bn2g[c] * inv);
    float Bc = bn2b[c] + bn1b[c];
    float S1 = bn1g[c] * inv;

    __shared__ __align__(16) float A[44*76];   // 13.4 KB
    __shared__ __align__(16) float Bf[44*72];  // 12.7 KB
    __shared__ float LpL[NM];
    const float* src = xc + (size_t)(b*NC + c) * XCS;
    int tid = threadIdx.x;

    if (tid < NM) LpL[tid] = Lp[b*640 + c*10 + tid];

    // stage0: load + bn0 -> A[44][76], zeros outside image
    for (int t = tid; t < 44*19; t += 256) {
        int r = t / 19, g2 = t - r*19;
        int gy = R0 - 6 + r, gx0 = C0 - 6 + 4*g2;
        float4 v = make_float4(0.f, 0.f, 0.f, 0.f);
        bool rowOK = (unsigned)gy < NH;
        if (rowOK) {
            const float* rowp = src + gy*NW;
            if ((unsigned)gx0 <= (unsigned)(NW-4)) {
                v = *(const float4*)(rowp + gx0);
            } else {
                float* pv = (float*)&v;
#pragma unroll
                for (int u = 0; u < 4; ++u) {
                    int gx = gx0 + u;
                    if ((unsigned)gx < NW) pv[u] = rowp[gx];
                }
            }
        }
        float4 w;
        w.x = (rowOK && (unsigned)(gx0+0) < NW) ? fmaf(v.x, s0, b0) : 0.f;
        w.y = (rowOK && (unsigned)(gx0+1) < NW) ? fmaf(v.y, s0, b0) : 0.f;
        w.z = (rowOK && (unsigned)(gx0+2) < NW) ? fmaf(v.z, s0, b0) : 0.f;
        w.w = (rowOK && (unsigned)(gx0+3) < NW) ? fmaf(v.w, s0, b0) : 0.f;
        *(float4*)&A[r*76 + 4*g2] = w;
    }
    __syncthreads();

    // stage1: horizontal 1x5 (+-2) + bn1 -> Bf[44][72]
    for (int t = tid; t < 44*18; t += 256) {
        int r = t / 18, g2 = t - r*18;
        float xw[8];
        *(float4*)&xw[0] = *(float4*)&A[r*76 + 4*g2];
        *(float4*)&xw[4] = *(float4*)&A[r*76 + 4*g2 + 4];
        int gy = R0 - 6 + r;
        bool rowOK = (unsigned)gy < NH;
        float o[4];
#pragma unroll
        for (int u = 0; u < 4; ++u) {
            float acc = 0.f;
#pragma unroll
            for (int q = 0; q < 5; ++q) acc = fmaf(w1[q], xw[u+q], acc);
            int gx = C0 - 4 + 4*g2 + u;
            o[u] = (rowOK && (unsigned)gx < NW) ? fmaf(acc, s1, b1) : 0.f;
        }
        *(float4*)&Bf[r*72 + 4*g2] = *(float4*)o;
    }
    __syncthreads();

    // stage2: vertical 5x1 (+-2) + bn2 -> A[40][72]
    for (int t = tid; t < 40*18; t += 256) {
        int r = t / 18, g2 = t - r*18;
        float ys[5][4];
#pragma unroll
        for (int p = 0; p < 5; ++p)
            *(float4*)&ys[p][0] = *(float4*)&Bf[(r+p)*72 + 4*g2];
        int gy = R0 - 4 + r;
        bool rowOK = (unsigned)gy < NH;
        float o[4];
#pragma unroll
        for (int u = 0; u < 4; ++u) {
            float acc = 0.f;
#pragma unroll
            for (int p = 0; p < 5; ++p) acc = fmaf(w2[p], ys[p][u], acc);
            int gx = C0 - 4 + 4*g2 + u;
            o[u] = (rowOK && (unsigned)gx < NW) ? fmaf(acc, s2, b2) : 0.f;
        }
        *(float4*)&A[r*72 + 4*g2] = *(float4*)o;
    }
    __syncthreads();

    // stage3: horizontal 1x5 dil2 (+-4) + bn3 -> Bf[40][64]
    for (int t = tid; t < 40*16; t += 256) {
        int r = t >> 4, g2 = t & 15;
        float xw[12];
        *(float4*)&xw[0] = *(float4*)&A[r*72 + 4*g2];
        *(float4*)&xw[4] = *(float4*)&A[r*72 + 4*g2 + 4];
        *(float4*)&xw[8] = *(float4*)&A[r*72 + 4*g2 + 8];
        int gy = R0 - 4 + r;
        bool rowOK = (unsigned)gy < NH;
        float o[4];
#pragma unroll
        for (int u = 0; u < 4; ++u) {
            float acc = 0.f;
#pragma unroll
            for (int q = 0; q < 5; ++q) acc = fmaf(w3[q], xw[u+2*q], acc);
            o[u] = rowOK ? fmaf(acc, s3, b3) : 0.f;
        }
        *(float4*)&Bf[r*64 + 4*g2] = *(float4*)o;
    }
    __syncthreads();

    // stage4: vertical 5x1 dil2 (+-4) + bn4 -> x_center (regs), then fusion
    const float* vgb = vg + (size_t)b * NM * NHW;
    const float* Sfb = Sf + (size_t)b * NHW;
    for (int t = tid; t < 32*16; t += 256) {
        int r = t >> 4, g2 = t & 15;
        float ys[5][4];
#pragma unroll
        for (int p = 0; p < 5; ++p)
            *(float4*)&ys[p][0] = *(float4*)&Bf[(r+2*p)*64 + 4*g2];
        int kbase = (R0 + r) * NW + C0 + 4*g2;
        size_t xbase = (size_t)(b*NC + c) * NHW + kbase;
        float4 xv = *(const float4*)&x[xbase];
        float4 skv = *(const float4*)&Sfb[kbase];
        const float* xvp = (const float*)&xv;
        const float* skp = (const float*)&skv;
        float vr[NM][4];
#pragma unroll
        for (int i = 0; i < NM; ++i)
            *(float4*)&vr[i][0] = *(const float4*)&vgb[i * NHW + kbase];
        float res[4];
#pragma unroll
        for (int u = 0; u < 4; ++u) {
            float acc = 0.f;
#pragma unroll
            for (int p = 0; p < 5; ++p) acc = fmaf(w4[p], ys[p][u], acc);
            float xcen = fmaf(acc, s4, b4);
            float R = 0.f;
#pragma unroll
            for (int i = 0; i < NM; ++i) R = fmaf(LpL[i], vr[i][u], R);
            float pre = fmaf(Ac, skp[u], Bc) + S1 * R + xcen;
            float att = 1.0f / (1.0f + expf(-pre));
            res[u] = xvp[u] * att;
        }
        *(float4*)&out[xbase] = *(float4*)res;
    }
}

// ---------------------------------------------------------------------------
extern "C" void kernel_launch(void* const* d_in, const int* in_sizes, int n_in,
                              void* d_out, int out_size, void* d_ws, size_t ws_size,
                              hipStream_t stream) {
    (void)in_sizes; (void)n_in; (void)out_size; (void)ws_size;
    const float* x      = (const float*)d_in[0];
    const float* wconv1 = (const float*)d_in[1];
    const float* pw1    = (const float*)d_in[2];
    const float* pw2    = (const float*)d_in[3];
    const float* pw3    = (const float*)d_in[4];
    const float* pw4    = (const float*)d_in[5];
    const float* pgam   = (const float*)d_in[6];
    const float* pbet   = (const float*)d_in[7];
    const float* bn1g   = (const float*)d_in[8];
    const float* bn1b   = (const float*)d_in[9];
    const float* bn2g   = (const float*)d_in[10];
    const float* bn2b   = (const float*)d_in[11];
    const float* fc1w   = (const float*)d_in[12];
    const float* fc1b   = (const float*)d_in[13];
    const float* ph1w   = (const float*)d_in[14];
    const float* ph1b   = (const float*)d_in[15];
    const float* ph2w   = (const float*)d_in[16];
    const float* ph2b   = (const float*)d_in[17];
    const float* ph3w   = (const float*)d_in[18];
    const float* ph3b   = (const float*)d_in[19];
    const float* wconv2 = (const float*)d_in[20];
    float* out = (float*)d_out;

    // workspace layout (~81 MB), padded xc first, doubles 8B-aligned
    float*  ws    = (float*)d_ws;
    float*  xc    = ws;                                 // 1024*16416 f32 (67.2MB)
    double* Sd    = (double*)(ws + 1024 * XCS);         // 262144 f64 (2MB)
    double* g     = Sd + NB * NHW;                      // 1024 f64
    double* lev   = g + NB * NC;                        // 160 f64
    double* gn    = lev + NB * NM;                      // 16 f64
    double* pmn   = gn + NB;                            // 64 f64
    double* pmx   = pmn + 64;                           // 64 f64
    double* pbins = pmx + 64;                           // 640 f64
    float*  Lp    = (float*)(pbins + 640);              // 10240 f32
    float*  vg    = Lp + NB * 640;                      // 2621440 f32 (10.5MB)
    float*  Sf    = vg + NB * NM * NHW;                 // 262144 f32 (1MB)
    float*  Wt    = Sf + NB * NHW;                      // 4096 f32

    k_gmean<<<NB * NC, 256, 0, stream>>>(x, g);
    k_misc<<<17, 256, 0, stream>>>(wconv1, g, Wt, gn);
    k_conv1_S<<<NB * NHW / 256, 256, 0, stream>>>(x, Wt, g, gn, xc, Sd);
    k_minmax<<<NB * 4, 256, 0, stream>>>(Sd, pmn, pmx);
    k_hist<<<NB * 4, 256, 0, stream>>>(Sd, pmn, pmx, pbins);
    k_chain<<<NB, 256, 0, stream>>>(pmn, pmx, pbins, fc1w, fc1b,
                                    ph1w, ph1b, ph2w, ph2b, ph3w, ph3b,
                                    lev, Lp);
    k_vgath<<<NB * NHW / 256, 256, 0, stream>>>(Sd, lev, vg, Sf);
    k_dwfinal<<<dim3(8, NC, NB), 256, 0, stream>>>(
        xc, x, vg, Sf, Lp, pw1, pw2, pw3, pw4, pgam, pbet,
        bn1g, bn1b, bn2g, bn2b, wconv2, out);
}